// Round 4
// baseline (123.064 us; speedup 1.0000x reference)
//
#include <hip/hip_runtime.h>
#include <hip/hip_bf16.h>

// Problem constants (from reference)
#define B_GRAPHS 16384
#define NODES_PER_G 50
#define REPR 128          // (1+L)*EMB
#define PFEAT 1280
#define FEAT 200
#define EMB 32
#define P_ROWS 2000
#define D_ROWS 10000

#define NPF (P_ROWS / 8)            // 250 protein-fuse blocks
#define NDF (D_ROWS / 8)            // 1250 drug-fuse blocks
#define NFUSE (NPF + NDF)           // 1500
#define NPOOL (B_GRAPHS / 8)        // 2048 pool blocks

// ws layout (floats): [0 .. 2*P_ROWS) fuse1-dot [P][2];
//                     [2*P_ROWS ..) fuse2-dot [D][2]

// ---------------------------------------------------------------------------
// Merged kernel. Block roles by blockIdx.x:
//   [0, NPOOL)            : graph pooling (pure HBM stream) -> PARTIAL out
//   [NPOOL, +NPF)         : protein fuse rows (dedup'd fuse1 MLP)
//   [NPOOL+NPF, +NDF)     : drug fuse rows    (dedup'd fuse2 MLP)
// Pool blocks FIRST: the HBM stream fills the whole machine immediately;
// L2-bound fuse blocks backfill CU slots as pool blocks retire (drain tail).
// ---------------------------------------------------------------------------
__global__ __launch_bounds__(256) void merged_kernel(
    const float* __restrict__ nr,        // node_repr [N][128]
    const float* __restrict__ profeat,   // [P][1280]
    const float* __restrict__ drugfeat,  // [D][200]
    const float* __restrict__ W1p,       // [1280][32]
    const float* __restrict__ b1p,       // [32]
    const float* __restrict__ W2p,       // [32][32]
    const float* __restrict__ W1,        // [200][32]
    const float* __restrict__ b1,        // [32]
    const float* __restrict__ W2,        // [32][32]
    const float* __restrict__ fcW,       // [448][2]
    const float* __restrict__ b2p,       // [32]
    const float* __restrict__ b2,        // [32]
    float*       __restrict__ f1out,     // [P][2]
    float*       __restrict__ f2out,     // [D][2]
    float*       __restrict__ out)       // [B][2] (partial)
{
    const int grp  = threadIdx.x >> 5;
    const int lane = threadIdx.x & 31;
    const int bid  = blockIdx.x;

    if (bid < NPOOL) {
        // ---------------- graph pooling (pure stream) ----------------
        const int g = bid * 8 + grp;
        const float4* nr4 = (const float4*)nr;
        const long base4 = (long)g * (NODES_PER_G * REPR / 4);  // g*1600

        float4 head4 = nr4[base4 + 0 * 32 + lane];
        float4 tail4 = nr4[base4 + 1 * 32 + lane];
        // 4 independent accumulators, 4 address-independent loads per body
        float4 s0, s1, s2, s3;
        s0.x = s0.y = s0.z = s0.w = 0.f;
        s1.x = s1.y = s1.z = s1.w = 0.f;
        s2.x = s2.y = s2.z = s2.w = 0.f;
        s3.x = s3.y = s3.z = s3.w = 0.f;
        #pragma unroll 4
        for (int i = 2; i < NODES_PER_G; i += 4) {   // 48 rows: i=2..46
            float4 fa = nr4[base4 + (i + 0) * 32 + lane];
            float4 fb = nr4[base4 + (i + 1) * 32 + lane];
            float4 fc = nr4[base4 + (i + 2) * 32 + lane];
            float4 fd = nr4[base4 + (i + 3) * 32 + lane];
            s0.x += fa.x; s0.y += fa.y; s0.z += fa.z; s0.w += fa.w;
            s1.x += fb.x; s1.y += fb.y; s1.z += fb.z; s1.w += fb.w;
            s2.x += fc.x; s2.y += fc.y; s2.z += fc.z; s2.w += fc.w;
            s3.x += fd.x; s3.y += fd.y; s3.z += fd.z; s3.w += fd.w;
        }
        float4 pool;
        pool.x = (head4.x + tail4.x) + (s0.x + s1.x) + (s2.x + s3.x);
        pool.y = (head4.y + tail4.y) + (s0.y + s1.y) + (s2.y + s3.y);
        pool.z = (head4.z + tail4.z) + (s0.z + s1.z) + (s2.z + s3.z);
        pool.w = (head4.w + tail4.w) + (s0.w + s1.w) + (s2.w + s3.w);

        const float4* fcW4 = (const float4*)fcW;
        float4 wg0 = fcW4[lane * 2 + 0],       wg1 = fcW4[lane * 2 + 1];
        float4 wh0 = fcW4[64 + lane * 2 + 0],  wh1 = fcW4[64 + lane * 2 + 1];
        float4 wt0 = fcW4[128 + lane * 2 + 0], wt1 = fcW4[128 + lane * 2 + 1];

        const float inv50 = 1.0f / (float)NODES_PER_G;
        float p0 = inv50 * (pool.x * wg0.x + pool.y * wg0.z + pool.z * wg1.x + pool.w * wg1.z)
                 + head4.x * wh0.x + head4.y * wh0.z + head4.z * wh1.x + head4.w * wh1.z
                 + tail4.x * wt0.x + tail4.y * wt0.z + tail4.z * wt1.x + tail4.w * wt1.z;
        float p1 = inv50 * (pool.x * wg0.y + pool.y * wg0.w + pool.z * wg1.y + pool.w * wg1.w)
                 + head4.x * wh0.y + head4.y * wh0.w + head4.z * wh1.y + head4.w * wh1.w
                 + tail4.x * wt0.y + tail4.y * wt0.w + tail4.z * wt1.y + tail4.w * wt1.w;

        // constant bias pieces: b2p·fcW[384..416) and b2·fcW[416..448)
        {
            float2 fw1 = *(const float2*)(fcW + (384 + lane) * 2);
            float2 fw2 = *(const float2*)(fcW + (416 + lane) * 2);
            float bb1 = b2p[lane], bb2 = b2[lane];
            p0 = fmaf(bb1, fw1.x, fmaf(bb2, fw2.x, p0));
            p1 = fmaf(bb1, fw1.y, fmaf(bb2, fw2.y, p1));
        }

        for (int m = 16; m >= 1; m >>= 1) {
            p0 += __shfl_xor(p0, m, 32);
            p1 += __shfl_xor(p1, m, 32);
        }
        if (lane == 0) {
            out[g * 2 + 0] = p0;   // partial: fuse dots + fc_b added by finalize
            out[g * 2 + 1] = p1;
        }
    } else if (bid < NPOOL + NPF) {
        // ---------------- protein fuse ----------------
        const int p = (bid - NPOOL) * 8 + grp;
        float m0 = 0.f, m1 = 0.f;
        #pragma unroll
        for (int k = 0; k < 32; ++k) {
            float w = W2p[lane * 32 + k];
            float2 fw = *(const float2*)(fcW + (384 + k) * 2);
            m0 = fmaf(w, fw.x, m0);
            m1 = fmaf(w, fw.y, m1);
        }
        const float4* pf4 = (const float4*)(profeat + (long)p * PFEAT);
        float a0 = 0.f, a1 = 0.f, a2 = 0.f, a3 = 0.f;
        #pragma unroll 4
        for (int q = 0; q < PFEAT / 4; q += 4) {
            float4 f0 = pf4[q], f1 = pf4[q + 1], f2 = pf4[q + 2], f3 = pf4[q + 3];
            int k = q * 4;
            a0 = fmaf(f0.x, W1p[(k + 0) * 32 + lane], a0);
            a0 = fmaf(f0.y, W1p[(k + 1) * 32 + lane], a0);
            a0 = fmaf(f0.z, W1p[(k + 2) * 32 + lane], a0);
            a0 = fmaf(f0.w, W1p[(k + 3) * 32 + lane], a0);
            a1 = fmaf(f1.x, W1p[(k + 4) * 32 + lane], a1);
            a1 = fmaf(f1.y, W1p[(k + 5) * 32 + lane], a1);
            a1 = fmaf(f1.z, W1p[(k + 6) * 32 + lane], a1);
            a1 = fmaf(f1.w, W1p[(k + 7) * 32 + lane], a1);
            a2 = fmaf(f2.x, W1p[(k + 8) * 32 + lane], a2);
            a2 = fmaf(f2.y, W1p[(k + 9) * 32 + lane], a2);
            a2 = fmaf(f2.z, W1p[(k + 10) * 32 + lane], a2);
            a2 = fmaf(f2.w, W1p[(k + 11) * 32 + lane], a2);
            a3 = fmaf(f3.x, W1p[(k + 12) * 32 + lane], a3);
            a3 = fmaf(f3.y, W1p[(k + 13) * 32 + lane], a3);
            a3 = fmaf(f3.z, W1p[(k + 14) * 32 + lane], a3);
            a3 = fmaf(f3.w, W1p[(k + 15) * 32 + lane], a3);
        }
        float h = fmaxf((a0 + a1) + (a2 + a3) + b1p[lane], 0.f);
        float p0 = h * m0, p1 = h * m1;
        for (int m = 16; m >= 1; m >>= 1) {
            p0 += __shfl_xor(p0, m, 32);
            p1 += __shfl_xor(p1, m, 32);
        }
        if (lane == 0) {
            f1out[p * 2 + 0] = p0;
            f1out[p * 2 + 1] = p1;
        }
    } else {
        // ---------------- drug fuse ----------------
        const int d = (bid - NPOOL - NPF) * 8 + grp;
        float m0 = 0.f, m1 = 0.f;
        #pragma unroll
        for (int k = 0; k < 32; ++k) {
            float w = W2[lane * 32 + k];
            float2 fw = *(const float2*)(fcW + (416 + k) * 2);
            m0 = fmaf(w, fw.x, m0);
            m1 = fmaf(w, fw.y, m1);
        }
        const float4* df4 = (const float4*)(drugfeat + (long)d * FEAT);
        float a0 = 0.f, a1 = 0.f;
        #pragma unroll 5
        for (int q = 0; q < FEAT / 4; q += 2) {
            float4 f0 = df4[q], f1 = df4[q + 1];
            int k = q * 4;
            a0 = fmaf(f0.x, W1[(k + 0) * 32 + lane], a0);
            a0 = fmaf(f0.y, W1[(k + 1) * 32 + lane], a0);
            a0 = fmaf(f0.z, W1[(k + 2) * 32 + lane], a0);
            a0 = fmaf(f0.w, W1[(k + 3) * 32 + lane], a0);
            a1 = fmaf(f1.x, W1[(k + 4) * 32 + lane], a1);
            a1 = fmaf(f1.y, W1[(k + 5) * 32 + lane], a1);
            a1 = fmaf(f1.z, W1[(k + 6) * 32 + lane], a1);
            a1 = fmaf(f1.w, W1[(k + 7) * 32 + lane], a1);
        }
        float h = fmaxf(a0 + a1 + b1[lane], 0.f);
        float p0 = h * m0, p1 = h * m1;
        for (int m = 16; m >= 1; m >>= 1) {
            p0 += __shfl_xor(p0, m, 32);
            p1 += __shfl_xor(p1, m, 32);
        }
        if (lane == 0) {
            f2out[d * 2 + 0] = p0;
            f2out[d * 2 + 1] = p1;
        }
    }
}

// ---------------------------------------------------------------------------
// Finalize: one thread per graph. Dedup-table gathers + constant bias.
// Runs after merged_kernel (stream order), RMW on out.
// ---------------------------------------------------------------------------
__global__ __launch_bounds__(256) void finalize_kernel(
    const int*   __restrict__ head_ids,  // [B]
    const int*   __restrict__ tail_ids,  // [B]
    const int*   __restrict__ node_idx,  // [N]
    const int*   __restrict__ proind,    // [I]
    const int*   __restrict__ drugind,   // [I]
    const float* __restrict__ f1out,     // [P][2]
    const float* __restrict__ f2out,     // [D][2]
    const float* __restrict__ fcb,       // [2]
    float*       __restrict__ out)       // [B][2]
{
    const int g = blockIdx.x * 256 + threadIdx.x;
    if (g >= B_GRAPHS) return;
    const int prow = proind[node_idx[head_ids[g]]];
    const int drow = drugind[node_idx[tail_ids[g]]];
    const float2 f1v = *(const float2*)(f1out + prow * 2);
    const float2 f2v = *(const float2*)(f2out + drow * 2);
    float2 o = *(float2*)(out + g * 2);
    o.x += f1v.x + f2v.x + fcb[0];
    o.y += f1v.y + f2v.y + fcb[1];
    *(float2*)(out + g * 2) = o;
}

extern "C" void kernel_launch(void* const* d_in, const int* in_sizes, int n_in,
                              void* d_out, int out_size, void* d_ws, size_t ws_size,
                              hipStream_t stream) {
    const float* node_repr = (const float*)d_in[0];
    const float* profeat   = (const float*)d_in[1];
    const float* drugfeat  = (const float*)d_in[2];
    const float* W1p       = (const float*)d_in[3];
    const float* b1p       = (const float*)d_in[4];
    const float* W2p       = (const float*)d_in[5];
    const float* b2p       = (const float*)d_in[6];
    const float* W1        = (const float*)d_in[7];
    const float* b1        = (const float*)d_in[8];
    const float* W2        = (const float*)d_in[9];
    const float* b2        = (const float*)d_in[10];
    const float* fc_W      = (const float*)d_in[11];
    const float* fc_b      = (const float*)d_in[12];
    // d_in[13] = graph_ids (unused: blocks are contiguous, 50 nodes each)
    const int* head_ids    = (const int*)d_in[14];
    const int* tail_ids    = (const int*)d_in[15];
    const int* node_idx    = (const int*)d_in[16];
    const int* proind      = (const int*)d_in[17];
    const int* drugind     = (const int*)d_in[18];

    float* f1out = (float*)d_ws;                 // 2000*2 floats
    float* f2out = (float*)d_ws + 2 * P_ROWS;    // 10000*2 floats
    float* out   = (float*)d_out;

    hipLaunchKernelGGL(merged_kernel, dim3(NPOOL + NFUSE), dim3(256), 0, stream,
                       node_repr, profeat, drugfeat, W1p, b1p, W2p, W1, b1, W2,
                       fc_W, b2p, b2, f1out, f2out, out);

    hipLaunchKernelGGL(finalize_kernel, dim3(B_GRAPHS / 256), dim3(256), 0, stream,
                       head_ids, tail_ids, node_idx, proind, drugind,
                       f1out, f2out, fc_b, out);
}

// Round 5
// 107.337 us; speedup vs baseline: 1.1465x; 1.1465x over previous
//
#include <hip/hip_runtime.h>
#include <hip/hip_bf16.h>

// Problem constants (from reference)
#define B_GRAPHS 16384
#define NODES_PER_G 50
#define REPR 128          // (1+L)*EMB
#define PFEAT 1280
#define FEAT 200
#define EMB 32
#define P_ROWS 2000
#define D_ROWS 10000

#define NPF (P_ROWS / 8)            // 250 protein-fuse blocks
#define NDF (D_ROWS / 8)            // 1250 drug-fuse blocks
#define NFUSE (NPF + NDF)           // 1500
#define NPOOL (B_GRAPHS / 8)        // 2048 pool blocks
#define NTOT (NPOOL + NFUSE)        // 3548

// ws layout (floats): [0 .. 2*P_ROWS) fuse1-dot [P][2];
//                     [2*P_ROWS ..) fuse2-dot [D][2]

// ---------------------------------------------------------------------------
// Merged kernel with Bresenham-interleaved block roles: fuse blocks are
// spread uniformly through the dispatch order so their L2/VALU-bound work
// stays co-resident with (and hides under) the pool HBM stream, instead of
// forming a serial burst at the start (R3) or end (R4) of the kernel.
//   F(b) = floor(b*NFUSE/NTOT); block b is fuse iff F(b+1)>F(b).
// ---------------------------------------------------------------------------
__global__ __launch_bounds__(256) void merged_kernel(
    const float* __restrict__ nr,        // node_repr [N][128]
    const float* __restrict__ profeat,   // [P][1280]
    const float* __restrict__ drugfeat,  // [D][200]
    const float* __restrict__ W1p,       // [1280][32]
    const float* __restrict__ b1p,       // [32]
    const float* __restrict__ W2p,       // [32][32]
    const float* __restrict__ W1,        // [200][32]
    const float* __restrict__ b1,        // [32]
    const float* __restrict__ W2,        // [32][32]
    const float* __restrict__ fcW,       // [448][2]
    const float* __restrict__ b2p,       // [32]
    const float* __restrict__ b2,        // [32]
    float*       __restrict__ f1out,     // [P][2]
    float*       __restrict__ f2out,     // [D][2]
    float*       __restrict__ out)       // [B][2] (partial)
{
    const int grp  = threadIdx.x >> 5;
    const int lane = threadIdx.x & 31;
    const int bid  = blockIdx.x;

    const int Fb  = (int)(((long)bid * NFUSE) / NTOT);
    const int Fb1 = (int)(((long)(bid + 1) * NFUSE) / NTOT);

    if (Fb1 == Fb) {
        // ---------------- graph pooling (pure stream) ---------------- [R3 verbatim]
        const int g = (bid - Fb) * 8 + grp;
        const float4* nr4 = (const float4*)nr;
        const long base4 = (long)g * (NODES_PER_G * REPR / 4);  // g*1600

        float4 head4 = nr4[base4 + 0 * 32 + lane];
        float4 tail4 = nr4[base4 + 1 * 32 + lane];
        float4 s0, s1;
        s0.x = s0.y = s0.z = s0.w = 0.f;
        s1.x = s1.y = s1.z = s1.w = 0.f;
        #pragma unroll 8
        for (int i = 2; i < NODES_PER_G; i += 2) {
            float4 fa = nr4[base4 + i * 32 + lane];
            float4 fb = nr4[base4 + (i + 1) * 32 + lane];
            s0.x += fa.x; s0.y += fa.y; s0.z += fa.z; s0.w += fa.w;
            s1.x += fb.x; s1.y += fb.y; s1.z += fb.z; s1.w += fb.w;
        }
        float4 pool;
        pool.x = head4.x + tail4.x + s0.x + s1.x;
        pool.y = head4.y + tail4.y + s0.y + s1.y;
        pool.z = head4.z + tail4.z + s0.z + s1.z;
        pool.w = head4.w + tail4.w + s0.w + s1.w;

        const float4* fcW4 = (const float4*)fcW;
        float4 wg0 = fcW4[lane * 2 + 0],       wg1 = fcW4[lane * 2 + 1];
        float4 wh0 = fcW4[64 + lane * 2 + 0],  wh1 = fcW4[64 + lane * 2 + 1];
        float4 wt0 = fcW4[128 + lane * 2 + 0], wt1 = fcW4[128 + lane * 2 + 1];

        const float inv50 = 1.0f / (float)NODES_PER_G;
        float p0 = inv50 * (pool.x * wg0.x + pool.y * wg0.z + pool.z * wg1.x + pool.w * wg1.z)
                 + head4.x * wh0.x + head4.y * wh0.z + head4.z * wh1.x + head4.w * wh1.z
                 + tail4.x * wt0.x + tail4.y * wt0.z + tail4.z * wt1.x + tail4.w * wt1.z;
        float p1 = inv50 * (pool.x * wg0.y + pool.y * wg0.w + pool.z * wg1.y + pool.w * wg1.w)
                 + head4.x * wh0.y + head4.y * wh0.w + head4.z * wh1.y + head4.w * wh1.w
                 + tail4.x * wt0.y + tail4.y * wt0.w + tail4.z * wt1.y + tail4.w * wt1.w;

        // constant bias pieces: b2p·fcW[384..416) and b2·fcW[416..448)
        {
            float2 fw1 = *(const float2*)(fcW + (384 + lane) * 2);
            float2 fw2 = *(const float2*)(fcW + (416 + lane) * 2);
            float bb1 = b2p[lane], bb2 = b2[lane];
            p0 = fmaf(bb1, fw1.x, fmaf(bb2, fw2.x, p0));
            p1 = fmaf(bb1, fw1.y, fmaf(bb2, fw2.y, p1));
        }

        for (int m = 16; m >= 1; m >>= 1) {
            p0 += __shfl_xor(p0, m, 32);
            p1 += __shfl_xor(p1, m, 32);
        }
        if (lane == 0) {
            out[g * 2 + 0] = p0;   // partial: fuse dots + fc_b added by finalize
            out[g * 2 + 1] = p1;
        }
    } else if (Fb < NPF) {
        // ---------------- protein fuse ---------------- [R3 verbatim]
        const int p = Fb * 8 + grp;
        float m0 = 0.f, m1 = 0.f;
        #pragma unroll
        for (int k = 0; k < 32; ++k) {
            float w = W2p[lane * 32 + k];
            float2 fw = *(const float2*)(fcW + (384 + k) * 2);
            m0 = fmaf(w, fw.x, m0);
            m1 = fmaf(w, fw.y, m1);
        }
        const float4* pf4 = (const float4*)(profeat + (long)p * PFEAT);
        float a0 = 0.f, a1 = 0.f, a2 = 0.f, a3 = 0.f;
        #pragma unroll 4
        for (int q = 0; q < PFEAT / 4; q += 4) {
            float4 f0 = pf4[q], f1 = pf4[q + 1], f2 = pf4[q + 2], f3 = pf4[q + 3];
            int k = q * 4;
            a0 = fmaf(f0.x, W1p[(k + 0) * 32 + lane], a0);
            a0 = fmaf(f0.y, W1p[(k + 1) * 32 + lane], a0);
            a0 = fmaf(f0.z, W1p[(k + 2) * 32 + lane], a0);
            a0 = fmaf(f0.w, W1p[(k + 3) * 32 + lane], a0);
            a1 = fmaf(f1.x, W1p[(k + 4) * 32 + lane], a1);
            a1 = fmaf(f1.y, W1p[(k + 5) * 32 + lane], a1);
            a1 = fmaf(f1.z, W1p[(k + 6) * 32 + lane], a1);
            a1 = fmaf(f1.w, W1p[(k + 7) * 32 + lane], a1);
            a2 = fmaf(f2.x, W1p[(k + 8) * 32 + lane], a2);
            a2 = fmaf(f2.y, W1p[(k + 9) * 32 + lane], a2);
            a2 = fmaf(f2.z, W1p[(k + 10) * 32 + lane], a2);
            a2 = fmaf(f2.w, W1p[(k + 11) * 32 + lane], a2);
            a3 = fmaf(f3.x, W1p[(k + 12) * 32 + lane], a3);
            a3 = fmaf(f3.y, W1p[(k + 13) * 32 + lane], a3);
            a3 = fmaf(f3.z, W1p[(k + 14) * 32 + lane], a3);
            a3 = fmaf(f3.w, W1p[(k + 15) * 32 + lane], a3);
        }
        float h = fmaxf((a0 + a1) + (a2 + a3) + b1p[lane], 0.f);
        float p0 = h * m0, p1 = h * m1;
        for (int m = 16; m >= 1; m >>= 1) {
            p0 += __shfl_xor(p0, m, 32);
            p1 += __shfl_xor(p1, m, 32);
        }
        if (lane == 0) {
            f1out[p * 2 + 0] = p0;
            f1out[p * 2 + 1] = p1;
        }
    } else {
        // ---------------- drug fuse ---------------- [R3 verbatim]
        const int d = (Fb - NPF) * 8 + grp;
        float m0 = 0.f, m1 = 0.f;
        #pragma unroll
        for (int k = 0; k < 32; ++k) {
            float w = W2[lane * 32 + k];
            float2 fw = *(const float2*)(fcW + (416 + k) * 2);
            m0 = fmaf(w, fw.x, m0);
            m1 = fmaf(w, fw.y, m1);
        }
        const float4* df4 = (const float4*)(drugfeat + (long)d * FEAT);
        float a0 = 0.f, a1 = 0.f;
        #pragma unroll 5
        for (int q = 0; q < FEAT / 4; q += 2) {
            float4 f0 = df4[q], f1 = df4[q + 1];
            int k = q * 4;
            a0 = fmaf(f0.x, W1[(k + 0) * 32 + lane], a0);
            a0 = fmaf(f0.y, W1[(k + 1) * 32 + lane], a0);
            a0 = fmaf(f0.z, W1[(k + 2) * 32 + lane], a0);
            a0 = fmaf(f0.w, W1[(k + 3) * 32 + lane], a0);
            a1 = fmaf(f1.x, W1[(k + 4) * 32 + lane], a1);
            a1 = fmaf(f1.y, W1[(k + 5) * 32 + lane], a1);
            a1 = fmaf(f1.z, W1[(k + 6) * 32 + lane], a1);
            a1 = fmaf(f1.w, W1[(k + 7) * 32 + lane], a1);
        }
        float h = fmaxf(a0 + a1 + b1[lane], 0.f);
        float p0 = h * m0, p1 = h * m1;
        for (int m = 16; m >= 1; m >>= 1) {
            p0 += __shfl_xor(p0, m, 32);
            p1 += __shfl_xor(p1, m, 32);
        }
        if (lane == 0) {
            f2out[d * 2 + 0] = p0;
            f2out[d * 2 + 1] = p1;
        }
    }
}

// ---------------------------------------------------------------------------
// Finalize: one thread per graph. Dedup-table gathers + constant bias.
// ---------------------------------------------------------------------------
__global__ __launch_bounds__(256) void finalize_kernel(
    const int*   __restrict__ head_ids,  // [B]
    const int*   __restrict__ tail_ids,  // [B]
    const int*   __restrict__ node_idx,  // [N]
    const int*   __restrict__ proind,    // [I]
    const int*   __restrict__ drugind,   // [I]
    const float* __restrict__ f1out,     // [P][2]
    const float* __restrict__ f2out,     // [D][2]
    const float* __restrict__ fcb,       // [2]
    float*       __restrict__ out)       // [B][2]
{
    const int g = blockIdx.x * 256 + threadIdx.x;
    if (g >= B_GRAPHS) return;
    const int prow = proind[node_idx[head_ids[g]]];
    const int drow = drugind[node_idx[tail_ids[g]]];
    const float2 f1v = *(const float2*)(f1out + prow * 2);
    const float2 f2v = *(const float2*)(f2out + drow * 2);
    float2 o = *(float2*)(out + g * 2);
    o.x += f1v.x + f2v.x + fcb[0];
    o.y += f1v.y + f2v.y + fcb[1];
    *(float2*)(out + g * 2) = o;
}

extern "C" void kernel_launch(void* const* d_in, const int* in_sizes, int n_in,
                              void* d_out, int out_size, void* d_ws, size_t ws_size,
                              hipStream_t stream) {
    const float* node_repr = (const float*)d_in[0];
    const float* profeat   = (const float*)d_in[1];
    const float* drugfeat  = (const float*)d_in[2];
    const float* W1p       = (const float*)d_in[3];
    const float* b1p       = (const float*)d_in[4];
    const float* W2p       = (const float*)d_in[5];
    const float* b2p       = (const float*)d_in[6];
    const float* W1        = (const float*)d_in[7];
    const float* b1        = (const float*)d_in[8];
    const float* W2        = (const float*)d_in[9];
    const float* b2        = (const float*)d_in[10];
    const float* fc_W      = (const float*)d_in[11];
    const float* fc_b      = (const float*)d_in[12];
    // d_in[13] = graph_ids (unused: blocks are contiguous, 50 nodes each)
    const int* head_ids    = (const int*)d_in[14];
    const int* tail_ids    = (const int*)d_in[15];
    const int* node_idx    = (const int*)d_in[16];
    const int* proind      = (const int*)d_in[17];
    const int* drugind     = (const int*)d_in[18];

    float* f1out = (float*)d_ws;                 // 2000*2 floats
    float* f2out = (float*)d_ws + 2 * P_ROWS;    // 10000*2 floats
    float* out   = (float*)d_out;

    hipLaunchKernelGGL(merged_kernel, dim3(NTOT), dim3(256), 0, stream,
                       node_repr, profeat, drugfeat, W1p, b1p, W2p, W1, b1, W2,
                       fc_W, b2p, b2, f1out, f2out, out);

    hipLaunchKernelGGL(finalize_kernel, dim3(B_GRAPHS / 256), dim3(256), 0, stream,
                       head_ids, tail_ids, node_idx, proind, drugind,
                       f1out, f2out, fc_b, out);
}